// Round 4
// baseline (156.014 us; speedup 1.0000x reference)
//
#include <hip/hip_runtime.h>

#define T_FRAMES 16384
#define N_MELS 128
#define N_FREQ 513
#define REPEAT 256
#define FPB 16             // frames per block
#define BT 512             // threads per block
#define LOG2_10 3.3219280948873623f

__global__ __launch_bounds__(BT, 8) void mel2lpc_kernel(
    const float* __restrict__ mel,   // [128][16384]
    const float* __restrict__ B,     // [513][128]
    const float* __restrict__ lag,   // [5]
    float* __restrict__ out)         // [4][16384*256]
{
  __shared__ float X_s[N_MELS][FPB];   // 8 KB: 10^mel tile
  __shared__ float W_s[5][N_FREQ];     // 10.3 KB
  __shared__ float red[8][5][FPB];     // 2.5 KB
  __shared__ float lp_s[4][FPB];       // 0.25 KB

  const int tid = threadIdx.x;
  const int t0 = blockIdx.x * FPB;

  // ---- Phase 0a: combined cosine/lag/norm table ----
  for (int idx = tid; idx < 5 * N_FREQ; idx += BT) {
    int k = idx / N_FREQ;
    int f = idx - k * N_FREQ;
    float cf = (f == 0 || f == N_FREQ - 1) ? (1.0f / 1024.0f) : (2.0f / 1024.0f);
    W_s[k][f] = lag[k] * cf * cospif((float)(k * f) * (1.0f / 512.0f));
  }
  // ---- Phase 0b: stage X = 10^mel into LDS (coalesced) ----
#pragma unroll
  for (int r = 0; r < 4; ++r) {
    int idx = r * BT + tid;            // 0..2047
    int m = idx >> 4;
    int t = idx & 15;
    X_s[m][t] = exp2f(mel[m * T_FRAMES + t0 + t] * LOG2_10);
  }
  __syncthreads();

  const int tg = tid & 7;     // frame group: frames tg*2, tg*2+1
  const int fg = tid >> 3;    // 0..63: freqs fg*8 .. fg*8+7
  const int f0 = fg * 8;

  const float4* __restrict__ B4 = (const float4*)B;    // [513][32]
  const float2* __restrict__ X2 = (const float2*)X_s;  // [128][8]

  // ---- Phase 1: register-tiled GEMM, 8f x 2t per thread ----
  float2 acc[8];
#pragma unroll
  for (int ff = 0; ff < 8; ++ff) acc[ff] = make_float2(0.f, 0.f);

#pragma unroll 4
  for (int ms = 0; ms < 32; ++ms) {    // m = 4*ms .. 4*ms+3
    float2 x0 = X2[(4 * ms + 0) * 8 + tg];
    float2 x1 = X2[(4 * ms + 1) * 8 + tg];
    float2 x2 = X2[(4 * ms + 2) * 8 + tg];
    float2 x3 = X2[(4 * ms + 3) * 8 + tg];
#pragma unroll
    for (int ff = 0; ff < 8; ++ff) {
      float4 b = B4[(f0 + ff) * 32 + ms];
      float2 a = acc[ff];
      a.x = fmaf(b.x, x0.x, a.x); a.x = fmaf(b.y, x1.x, a.x);
      a.x = fmaf(b.z, x2.x, a.x); a.x = fmaf(b.w, x3.x, a.x);
      a.y = fmaf(b.x, x0.y, a.y); a.y = fmaf(b.y, x1.y, a.y);
      a.y = fmaf(b.z, x2.y, a.y); a.y = fmaf(b.w, x3.y, a.y);
      acc[ff] = a;
    }
  }

  // ---- Phase 2: clamp/square + cosine-weighted partial sums ----
  float pk[5][2];
#pragma unroll
  for (int k = 0; k < 5; ++k)
#pragma unroll
    for (int j = 0; j < 2; ++j) pk[k][j] = 0.f;

#pragma unroll
  for (int ff = 0; ff < 8; ++ff) {
    float w0 = W_s[0][f0 + ff], w1 = W_s[1][f0 + ff], w2 = W_s[2][f0 + ff];
    float w3 = W_s[3][f0 + ff], w4 = W_s[4][f0 + ff];
    float2 a = acc[ff];
    float lin, p;
    lin = fmaxf(a.x, 1e-12f); p = lin * lin;
    pk[0][0] = fmaf(w0, p, pk[0][0]); pk[1][0] = fmaf(w1, p, pk[1][0]);
    pk[2][0] = fmaf(w2, p, pk[2][0]); pk[3][0] = fmaf(w3, p, pk[3][0]);
    pk[4][0] = fmaf(w4, p, pk[4][0]);
    lin = fmaxf(a.y, 1e-12f); p = lin * lin;
    pk[0][1] = fmaf(w0, p, pk[0][1]); pk[1][1] = fmaf(w1, p, pk[1][1]);
    pk[2][1] = fmaf(w2, p, pk[2][1]); pk[3][1] = fmaf(w3, p, pk[3][1]);
    pk[4][1] = fmaf(w4, p, pk[4][1]);
  }

  // ---- Phase 3: reduce fg groups within wave via shfl_xor, stash per wave ----
  const int wv = tid >> 6;
  const bool writer = (tid & 63) < 8;
#pragma unroll
  for (int k = 0; k < 5; ++k) {
#pragma unroll
    for (int j = 0; j < 2; ++j) {
      float v = pk[k][j];
      v += __shfl_xor(v, 8);
      v += __shfl_xor(v, 16);
      v += __shfl_xor(v, 32);
      if (writer) red[wv][k][tg * 2 + j] = v;
    }
  }
  __syncthreads();

  // ---- Phase 4: final ac (+ f=512 row) + Levinson-Durbin, 1 lane/frame ----
  if (tid < FPB) {
    const int t = tid;
    float ac[5];
#pragma unroll
    for (int k = 0; k < 5; ++k) {
      float s = 0.f;
#pragma unroll
      for (int w = 0; w < 8; ++w) s += red[w][k][t];
      ac[k] = s;
    }
    // remainder frequency row f = 512
    float s = 0.f;
    const float* __restrict__ Bl = B + 512 * N_MELS;
#pragma unroll
    for (int m = 0; m < N_MELS; ++m) s = fmaf(Bl[m], X_s[m][t], s);
    float lin = fmaxf(s, 1e-12f);
    float p = lin * lin;
#pragma unroll
    for (int k = 0; k < 5; ++k) ac[k] = fmaf(W_s[k][512], p, ac[k]);

    float E = ac[0];
    float k0 = ac[1] / E;
    E *= fmaxf(1.0f - k0 * k0, 1e-5f);
    float l0 = -k0;

    float a1 = ac[2] + l0 * ac[1];
    float k1 = a1 / E;
    E *= fmaxf(1.0f - k1 * k1, 1e-5f);
    float m0 = l0 - k1 * l0;
    float m1 = -k1;

    float a2 = ac[3] + m0 * ac[2] + m1 * ac[1];
    float k2 = a2 / E;
    E *= fmaxf(1.0f - k2 * k2, 1e-5f);
    float n0 = m0 - k2 * m1;
    float n1 = m1 - k2 * m0;
    float n2 = -k2;

    float a3 = ac[4] + n0 * ac[3] + n1 * ac[2] + n2 * ac[1];
    float k3 = a3 / E;
    float o0 = n0 - k3 * n2;
    float o1 = n1 - k3 * n1;
    float o2 = n2 - k3 * n0;
    float o3 = -k3;

    lp_s[0][t] = -o3;
    lp_s[1][t] = -o2;
    lp_s[2][t] = -o1;
    lp_s[3][t] = -o0;
  }
  __syncthreads();

  // ---- Phase 5: repeat-expand write, coalesced float4 ----
  // per block: 4 rows x 16 frames x 256 reps = 16384 floats = 4096 float4
  float4* out4 = (float4*)out;
#pragma unroll
  for (int i = 0; i < 8; ++i) {
    int vid = i * BT + tid;       // 0..4095
    int j = vid >> 10;            // output row 0..3
    int rem = vid & 1023;         // float4 idx within this block's row chunk
    int tl = rem >> 6;            // local frame 0..15 (wave-uniform)
    float v = lp_s[j][tl];
    out4[(size_t)j * (T_FRAMES * REPEAT / 4) + (size_t)t0 * 64 + rem] =
        make_float4(v, v, v, v);
  }
}

extern "C" void kernel_launch(void* const* d_in, const int* in_sizes, int n_in,
                              void* d_out, int out_size, void* d_ws, size_t ws_size,
                              hipStream_t stream) {
  const float* mel = (const float*)d_in[0];
  const float* B   = (const float*)d_in[1];
  const float* lag = (const float*)d_in[2];
  float* out = (float*)d_out;
  mel2lpc_kernel<<<T_FRAMES / FPB, BT, 0, stream>>>(mel, B, lag, out);
}

// Round 5
// 132.813 us; speedup vs baseline: 1.1747x; 1.1747x over previous
//
#include <hip/hip_runtime.h>

#define T_FRAMES 16384
#define N_MELS 128
#define N_FREQ 513
#define REPEAT 256
#define FPB 32
#define BT 512
#define LOG2_10 3.3219280948873623f
#define NCHUNK 16            // m-chunks of 8
#define CHUNK_BYTES 16384    // 512 rows * 32 B

typedef __attribute__((address_space(3))) char lds_char_t;
typedef __attribute__((address_space(1))) const char glob_char_t;

// ---- Kernel 0: build pre-swizzled B image in ws -------------------------
// image chunk c holds B[:, 8c..8c+7]; float4 (row, j) stored at byte
// c*16384 + ((row*32 + j*16) ^ ((row & 0x38) << 1))   (XOR bank swizzle)
__global__ __launch_bounds__(256) void build_bimg(
    const float* __restrict__ B, float* __restrict__ img) {
  int idx = blockIdx.x * 256 + threadIdx.x;   // 0..16383 float4s
  int row = idx >> 5;
  int c = (idx >> 1) & 15;
  int j = idx & 1;
  float4 v = ((const float4*)B)[row * 32 + c * 2 + j];
  int byte = c * CHUNK_BYTES + ((row * 32 + j * 16) ^ ((row & 0x38) << 1));
  *(float4*)((char*)img + byte) = v;
}

// ---- Kernel A: GEMM + cosine transform + Levinson -> lpc[4][16384] ------
#define FMA_MI(bc, xvN)                                            \
  a.x = fmaf(bc, xvN.x, a.x); a.y = fmaf(bc, xvN.y, a.y);          \
  a.z = fmaf(bc, xvN.z, a.z); a.w = fmaf(bc, xvN.w, a.w);

__global__ __launch_bounds__(BT, 4) void mel2lpc_gemm(
    const float* __restrict__ mel,   // [128][16384]
    const float* __restrict__ B,     // [513][128] (row 512 only)
    const float* __restrict__ lag,   // [5]
    const float* __restrict__ bimg,  // swizzled B image (ws)
    float* __restrict__ lpcw)        // [4][16384] (ws)
{
  __shared__ __align__(16) char Bb[2][CHUNK_BYTES];   // 32 KB dbuf
  __shared__ float X_s[N_MELS][FPB];                  // 16 KB
  __shared__ float W_s[5][N_FREQ];                    // 10.3 KB
  __shared__ float red[8][5][FPB];                    // 5 KB

  const int tid = threadIdx.x;
  const int t0 = blockIdx.x * FPB;
  const int lane = tid & 63;
  const int wv = __builtin_amdgcn_readfirstlane(tid >> 6);

  // stage chunk 0: each wave fills 2 x 1KB segments, dest linear
  {
    const char* g0 = (const char*)bimg + (2 * wv) * 1024 + lane * 16;
    __builtin_amdgcn_global_load_lds((glob_char_t*)g0,
        (lds_char_t*)&Bb[0][(2 * wv) * 1024], 16, 0, 0);
    __builtin_amdgcn_global_load_lds((glob_char_t*)(g0 + 1024),
        (lds_char_t*)&Bb[0][(2 * wv + 1) * 1024], 16, 0, 0);
  }

  // combined cosine/lag/norm table
  for (int idx = tid; idx < 5 * N_FREQ; idx += BT) {
    int k = idx / N_FREQ;
    int f = idx - k * N_FREQ;
    float cf = (f == 0 || f == N_FREQ - 1) ? (1.0f / 1024.0f) : (2.0f / 1024.0f);
    W_s[k][f] = lag[k] * cf * cospif((float)(k * f) * (1.0f / 512.0f));
  }
  // stage X = 10^mel
#pragma unroll
  for (int r = 0; r < 8; ++r) {
    int idx = r * BT + tid;
    int m = idx >> 5;
    int t = idx & 31;
    X_s[m][t] = exp2f(mel[m * T_FRAMES + t0 + t] * LOG2_10);
  }
  __syncthreads();   // drains gll(0) too

  const int tg = tid & 7;     // frames tg*4..tg*4+3
  const int fg = tid >> 3;    // rows fg*8..fg*8+7
  const int f0 = fg * 8;

  int boff[8];
#pragma unroll
  for (int ff = 0; ff < 8; ++ff) {
    int row = f0 + ff;
    boff[ff] = (row * 32) ^ ((row & 0x38) << 1);
  }

  float4 acc[8];
#pragma unroll
  for (int ff = 0; ff < 8; ++ff) acc[ff] = make_float4(0.f, 0.f, 0.f, 0.f);

  const float4* X4 = (const float4*)X_s;   // [128][8]

#pragma unroll 2
  for (int c = 0; c < NCHUNK; ++c) {
    const int p = c & 1;
    if (c + 1 < NCHUNK) {   // prefetch next slab into other buffer
      const char* g0 = (const char*)bimg + (c + 1) * CHUNK_BYTES
                       + (2 * wv) * 1024 + lane * 16;
      __builtin_amdgcn_global_load_lds((glob_char_t*)g0,
          (lds_char_t*)&Bb[p ^ 1][(2 * wv) * 1024], 16, 0, 0);
      __builtin_amdgcn_global_load_lds((glob_char_t*)(g0 + 1024),
          (lds_char_t*)&Bb[p ^ 1][(2 * wv + 1) * 1024], 16, 0, 0);
    }
    float4 xv[8];
#pragma unroll
    for (int mi = 0; mi < 8; ++mi) xv[mi] = X4[(c * 8 + mi) * 8 + tg];
#pragma unroll
    for (int ff = 0; ff < 8; ++ff) {
      float4 b0 = *(const float4*)&Bb[p][boff[ff]];
      float4 b1 = *(const float4*)&Bb[p][boff[ff] ^ 16];
      float4 a = acc[ff];
      FMA_MI(b0.x, xv[0]) FMA_MI(b0.y, xv[1])
      FMA_MI(b0.z, xv[2]) FMA_MI(b0.w, xv[3])
      FMA_MI(b1.x, xv[4]) FMA_MI(b1.y, xv[5])
      FMA_MI(b1.z, xv[6]) FMA_MI(b1.w, xv[7])
      acc[ff] = a;
    }
    __syncthreads();   // drains gll(c+1); releases Bb[p] for reuse
  }

  // clamp/square + cosine-weighted partial sums
  float pk[5][4];
#pragma unroll
  for (int k = 0; k < 5; ++k)
#pragma unroll
    for (int j = 0; j < 4; ++j) pk[k][j] = 0.f;

#pragma unroll
  for (int ff = 0; ff < 8; ++ff) {
    float w0 = W_s[0][f0 + ff], w1 = W_s[1][f0 + ff], w2 = W_s[2][f0 + ff];
    float w3 = W_s[3][f0 + ff], w4 = W_s[4][f0 + ff];
    float4 a = acc[ff];
    float lin, pv;
    lin = fmaxf(a.x, 1e-12f); pv = lin * lin;
    pk[0][0] = fmaf(w0, pv, pk[0][0]); pk[1][0] = fmaf(w1, pv, pk[1][0]);
    pk[2][0] = fmaf(w2, pv, pk[2][0]); pk[3][0] = fmaf(w3, pv, pk[3][0]);
    pk[4][0] = fmaf(w4, pv, pk[4][0]);
    lin = fmaxf(a.y, 1e-12f); pv = lin * lin;
    pk[0][1] = fmaf(w0, pv, pk[0][1]); pk[1][1] = fmaf(w1, pv, pk[1][1]);
    pk[2][1] = fmaf(w2, pv, pk[2][1]); pk[3][1] = fmaf(w3, pv, pk[3][1]);
    pk[4][1] = fmaf(w4, pv, pk[4][1]);
    lin = fmaxf(a.z, 1e-12f); pv = lin * lin;
    pk[0][2] = fmaf(w0, pv, pk[0][2]); pk[1][2] = fmaf(w1, pv, pk[1][2]);
    pk[2][2] = fmaf(w2, pv, pk[2][2]); pk[3][2] = fmaf(w3, pv, pk[3][2]);
    pk[4][2] = fmaf(w4, pv, pk[4][2]);
    lin = fmaxf(a.w, 1e-12f); pv = lin * lin;
    pk[0][3] = fmaf(w0, pv, pk[0][3]); pk[1][3] = fmaf(w1, pv, pk[1][3]);
    pk[2][3] = fmaf(w2, pv, pk[2][3]); pk[3][3] = fmaf(w3, pv, pk[3][3]);
    pk[4][3] = fmaf(w4, pv, pk[4][3]);
  }

  // reduce the 8 fg-subgroups within each wave (lane bits 3,4,5)
#pragma unroll
  for (int k = 0; k < 5; ++k) {
#pragma unroll
    for (int j = 0; j < 4; ++j) {
      float v = pk[k][j];
      v += __shfl_xor(v, 8);
      v += __shfl_xor(v, 16);
      v += __shfl_xor(v, 32);
      if (lane < 8) red[wv][k][tg * 4 + j] = v;
    }
  }
  __syncthreads();

  // final ac (+ f=512 row) + Levinson-Durbin, 1 lane/frame
  if (tid < FPB) {
    const int t = tid;
    float ac[5];
#pragma unroll
    for (int k = 0; k < 5; ++k) {
      float s = 0.f;
#pragma unroll
      for (int w = 0; w < 8; ++w) s += red[w][k][t];
      ac[k] = s;
    }
    float s = 0.f;
    const float* __restrict__ Bl = B + 512 * N_MELS;
#pragma unroll
    for (int m = 0; m < N_MELS; ++m) s = fmaf(Bl[m], X_s[m][t], s);
    float lin = fmaxf(s, 1e-12f);
    float pv = lin * lin;
#pragma unroll
    for (int k = 0; k < 5; ++k) ac[k] = fmaf(W_s[k][512], pv, ac[k]);

    float E = ac[0];
    float k0 = ac[1] / E;
    E *= fmaxf(1.0f - k0 * k0, 1e-5f);
    float l0 = -k0;

    float a1 = ac[2] + l0 * ac[1];
    float k1 = a1 / E;
    E *= fmaxf(1.0f - k1 * k1, 1e-5f);
    float m0 = l0 - k1 * l0;
    float m1 = -k1;

    float a2 = ac[3] + m0 * ac[2] + m1 * ac[1];
    float k2 = a2 / E;
    E *= fmaxf(1.0f - k2 * k2, 1e-5f);
    float n0 = m0 - k2 * m1;
    float n1 = m1 - k2 * m0;
    float n2 = -k2;

    float a3 = ac[4] + n0 * ac[3] + n1 * ac[2] + n2 * ac[1];
    float k3 = a3 / E;
    float o0 = n0 - k3 * n2;
    float o1 = n1 - k3 * n1;
    float o2 = n2 - k3 * n0;
    float o3 = -k3;

    lpcw[0 * T_FRAMES + t0 + t] = -o3;
    lpcw[1 * T_FRAMES + t0 + t] = -o2;
    lpcw[2 * T_FRAMES + t0 + t] = -o1;
    lpcw[3 * T_FRAMES + t0 + t] = -o0;
  }
}

// ---- Kernel B: repeat-expand, pure write-BW -----------------------------
__global__ __launch_bounds__(256) void expand(
    const float* __restrict__ lpc, float4* __restrict__ out4) {
  int g = blockIdx.x * 2048 + threadIdx.x;
#pragma unroll
  for (int i = 0; i < 8; ++i) {
    int gi = g + i * 256;
    int j = gi >> 20;                 // 2^20 float4 per output row
    int rem = gi & 1048575;
    int frame = rem >> 6;             // wave-uniform
    float v = lpc[j * T_FRAMES + frame];
    out4[gi] = make_float4(v, v, v, v);
  }
}

extern "C" void kernel_launch(void* const* d_in, const int* in_sizes, int n_in,
                              void* d_out, int out_size, void* d_ws, size_t ws_size,
                              hipStream_t stream) {
  const float* mel = (const float*)d_in[0];
  const float* B   = (const float*)d_in[1];
  const float* lag = (const float*)d_in[2];
  float* ws = (float*)d_ws;
  float* bimg = ws;                 // 256 KB swizzled B image
  float* lpcw = ws + 65536;         // 256 KB lpc[4][16384]
  build_bimg<<<64, 256, 0, stream>>>(B, bimg);
  mel2lpc_gemm<<<T_FRAMES / FPB, BT, 0, stream>>>(mel, B, lag, bimg, lpcw);
  expand<<<2048, 256, 0, stream>>>(lpcw, (float4*)d_out);
}

// Round 6
// 97.534 us; speedup vs baseline: 1.5996x; 1.3617x over previous
//
#include <hip/hip_runtime.h>

#define T_FRAMES 16384
#define N_MELS 128
#define N_FREQ 513
#define FPB 64             // frames per block
#define BT 512             // 8 waves
#define LOG2_10 3.3219280948873623f

typedef short bf16x8 __attribute__((ext_vector_type(8)));
typedef unsigned short u16x8 __attribute__((ext_vector_type(8)));
typedef float f32x4 __attribute__((ext_vector_type(4)));

__device__ __forceinline__ unsigned short f2bf(float x) {
  unsigned u = __float_as_uint(x);
  return (unsigned short)((u + 0x7FFFu + ((u >> 16) & 1u)) >> 16);
}
__device__ __forceinline__ float bf2f(unsigned short h) {
  return __uint_as_float(((unsigned)h) << 16);
}

// ---- Kernel 0: build frag-ready bf16 hi/lo image of B -------------------
// gid bit layout [w:3][ft:2][ks:2][hl:1][l:6]; lane l of frag (w,ft,ks,hl)
// holds B[f][k0..k0+8) as bf16, f = w*64+ft*16+(l&15), k0 = ks*32+(l>>4)*8.
__global__ __launch_bounds__(256) void build_bimg(
    const float* __restrict__ B, unsigned short* __restrict__ img) {
  int gid = blockIdx.x * 256 + threadIdx.x;   // 0..16383
  int l  = gid & 63;
  int hl = (gid >> 6) & 1;
  int ks = (gid >> 7) & 3;
  int ft = (gid >> 9) & 3;
  int w  = gid >> 11;
  int f  = w * 64 + ft * 16 + (l & 15);
  int k0 = ks * 32 + (l >> 4) * 8;
  const float* src = B + f * N_MELS + k0;
  u16x8 o;
#pragma unroll
  for (int j = 0; j < 8; ++j) {
    float x = src[j];
    unsigned short hi = f2bf(x);
    o[j] = hl ? f2bf(x - bf2f(hi)) : hi;
  }
  *((u16x8*)img + gid) = o;
}

// ---- Kernel A: MFMA GEMM + cosine transform + Levinson ------------------
__global__ __launch_bounds__(BT, 2) void mel2lpc_mfma(
    const float* __restrict__ mel,   // [128][16384]
    const float* __restrict__ B,     // [513][128] (row 512 only)
    const float* __restrict__ lag,   // [5]
    const unsigned short* __restrict__ bimg,
    float* __restrict__ lpcw)        // [4][16384]
{
  __shared__ float X32T[64][132];               // 33.8 KB, padded vs banks
  __shared__ __align__(16) short Xf[32][512];   // 32 KB: X frags (tt,ks,hl)
  __shared__ float W_s[5][N_FREQ];              // 10.3 KB
  __shared__ float red[8][5][64];               // 10 KB

  const int tid = threadIdx.x;
  const int lane = tid & 63;
  const int w = __builtin_amdgcn_readfirstlane(tid >> 6);
  const int t0 = blockIdx.x * FPB;

  // W[k][f] = lag[k]*cf*cos(2*pi*k*f/1024)
  for (int idx = tid; idx < 5 * N_FREQ; idx += BT) {
    int k = idx / N_FREQ;
    int f = idx - k * N_FREQ;
    float cf = (f == 0 || f == N_FREQ - 1) ? (1.0f / 1024.0f) : (2.0f / 1024.0f);
    W_s[k][f] = lag[k] * cf * cospif((float)(k * f) * (1.0f / 512.0f));
  }
  // stage X^T = 10^mel (coalesced reads; 2-way-free LDS writes)
#pragma unroll
  for (int r = 0; r < 16; ++r) {
    int idx = r * BT + tid;    // 0..8191
    int t = idx & 63;
    int m = idx >> 6;
    X32T[t][m] = exp2f(mel[m * T_FRAMES + t0 + t] * LOG2_10);
  }
  __syncthreads();

  // build X frags: B-operand layout, col=lane&15, k contiguous per lane
#pragma unroll
  for (int pi = 0; pi < 2; ++pi) {
    int pr = w * 2 + pi;            // 0..15 -> (tt,ks)
    int tt = pr >> 2, ks = pr & 3;
    int t = tt * 16 + (lane & 15);
    int k0 = ks * 32 + (lane >> 4) * 8;
    float4 a0 = *(const float4*)&X32T[t][k0];
    float4 a1 = *(const float4*)&X32T[t][k0 + 4];
    float xs[8] = {a0.x, a0.y, a0.z, a0.w, a1.x, a1.y, a1.z, a1.w};
    u16x8 vh, vl;
#pragma unroll
    for (int j = 0; j < 8; ++j) {
      unsigned short hi = f2bf(xs[j]);
      vh[j] = hi;
      vl[j] = f2bf(xs[j] - bf2f(hi));
    }
    int fi = (tt * 4 + ks) * 2;
    *(u16x8*)&Xf[fi][lane * 8] = vh;
    *(u16x8*)&Xf[fi + 1][lane * 8] = vl;
  }
  __syncthreads();

  // ---- MFMA GEMM: wave w owns f-rows [64w,64w+64) x 64 frames ----
  f32x4 acc[4][4];
#pragma unroll
  for (int ft = 0; ft < 4; ++ft)
#pragma unroll
    for (int tt = 0; tt < 4; ++tt) acc[ft][tt] = (f32x4){0.f, 0.f, 0.f, 0.f};

  const bf16x8* bfr = (const bf16x8*)bimg;
#pragma unroll
  for (int ks = 0; ks < 4; ++ks) {
    bf16x8 xh[4], xl[4], ah[4], al[4];
#pragma unroll
    for (int tt = 0; tt < 4; ++tt) {
      xh[tt] = *(const bf16x8*)&Xf[(tt * 4 + ks) * 2][lane * 8];
      xl[tt] = *(const bf16x8*)&Xf[(tt * 4 + ks) * 2 + 1][lane * 8];
    }
#pragma unroll
    for (int ft = 0; ft < 4; ++ft) {
      int fr = ((w * 4 + ft) * 4 + ks) * 2;
      ah[ft] = bfr[fr * 64 + lane];
      al[ft] = bfr[(fr + 1) * 64 + lane];
    }
#pragma unroll
    for (int ft = 0; ft < 4; ++ft)
#pragma unroll
      for (int tt = 0; tt < 4; ++tt) {
        acc[ft][tt] = __builtin_amdgcn_mfma_f32_16x16x32_bf16(ah[ft], xh[tt], acc[ft][tt], 0, 0, 0);
        acc[ft][tt] = __builtin_amdgcn_mfma_f32_16x16x32_bf16(ah[ft], xl[tt], acc[ft][tt], 0, 0, 0);
        acc[ft][tt] = __builtin_amdgcn_mfma_f32_16x16x32_bf16(al[ft], xh[tt], acc[ft][tt], 0, 0, 0);
      }
  }

  // ---- epilogue: clamp/square + cos-weighted reduce over f ----
  // C mapping: col = lane&15 (t), row = (lane>>4)*4 + j (f within tile)
  float pk[5][4];
#pragma unroll
  for (int k = 0; k < 5; ++k)
#pragma unroll
    for (int tt = 0; tt < 4; ++tt) pk[k][tt] = 0.f;

#pragma unroll
  for (int ft = 0; ft < 4; ++ft) {
#pragma unroll
    for (int j = 0; j < 4; ++j) {
      int f = w * 64 + ft * 16 + ((lane >> 4) << 2) + j;
      float w0 = W_s[0][f], w1 = W_s[1][f], w2 = W_s[2][f];
      float w3 = W_s[3][f], w4 = W_s[4][f];
#pragma unroll
      for (int tt = 0; tt < 4; ++tt) {
        float lin = fmaxf(acc[ft][tt][j], 1e-12f);
        float p = lin * lin;
        pk[0][tt] = fmaf(w0, p, pk[0][tt]);
        pk[1][tt] = fmaf(w1, p, pk[1][tt]);
        pk[2][tt] = fmaf(w2, p, pk[2][tt]);
        pk[3][tt] = fmaf(w3, p, pk[3][tt]);
        pk[4][tt] = fmaf(w4, p, pk[4][tt]);
      }
    }
  }
#pragma unroll
  for (int k = 0; k < 5; ++k)
#pragma unroll
    for (int tt = 0; tt < 4; ++tt) {
      float v = pk[k][tt];
      v += __shfl_xor(v, 16);
      v += __shfl_xor(v, 32);
      if (lane < 16) red[w][k][tt * 16 + lane] = v;
    }
  __syncthreads();

  // ---- final: cross-wave sum + f=512 row + Levinson-Durbin ----
  if (tid < 64) {
    const int t = tid;
    float ac[5];
#pragma unroll
    for (int k = 0; k < 5; ++k) {
      float s = 0.f;
#pragma unroll
      for (int w2 = 0; w2 < 8; ++w2) s += red[w2][k][t];
      ac[k] = s;
    }
    float s = 0.f;
    const float4* __restrict__ B512 = (const float4*)(B + 512 * N_MELS);
#pragma unroll
    for (int mi = 0; mi < 32; ++mi) {
      float4 b = B512[mi];
      float4 xv = *(const float4*)&X32T[t][mi * 4];
      s = fmaf(b.x, xv.x, s); s = fmaf(b.y, xv.y, s);
      s = fmaf(b.z, xv.z, s); s = fmaf(b.w, xv.w, s);
    }
    float lin = fmaxf(s, 1e-12f);
    float pv = lin * lin;
#pragma unroll
    for (int k = 0; k < 5; ++k) ac[k] = fmaf(W_s[k][512], pv, ac[k]);

    float E = ac[0];
    float k0 = ac[1] / E;
    E *= fmaxf(1.0f - k0 * k0, 1e-5f);
    float l0 = -k0;

    float a1 = ac[2] + l0 * ac[1];
    float k1 = a1 / E;
    E *= fmaxf(1.0f - k1 * k1, 1e-5f);
    float m0 = l0 - k1 * l0;
    float m1 = -k1;

    float a2 = ac[3] + m0 * ac[2] + m1 * ac[1];
    float k2 = a2 / E;
    E *= fmaxf(1.0f - k2 * k2, 1e-5f);
    float n0 = m0 - k2 * m1;
    float n1 = m1 - k2 * m0;
    float n2 = -k2;

    float a3 = ac[4] + n0 * ac[3] + n1 * ac[2] + n2 * ac[1];
    float k3 = a3 / E;
    float o0 = n0 - k3 * n2;
    float o1 = n1 - k3 * n1;
    float o2 = n2 - k3 * n0;
    float o3 = -k3;

    lpcw[0 * T_FRAMES + t0 + t] = -o3;
    lpcw[1 * T_FRAMES + t0 + t] = -o2;
    lpcw[2 * T_FRAMES + t0 + t] = -o1;
    lpcw[3 * T_FRAMES + t0 + t] = -o0;
  }
}

// ---- Kernel B: repeat-expand, pure write-BW -----------------------------
__global__ __launch_bounds__(256) void expand(
    const float* __restrict__ lpc, float4* __restrict__ out4) {
  int g = blockIdx.x * 2048 + threadIdx.x;
#pragma unroll
  for (int i = 0; i < 8; ++i) {
    int gi = g + i * 256;
    int j = gi >> 20;                 // 2^20 float4 per output row
    int rem = gi & 1048575;
    int frame = rem >> 6;             // wave-uniform
    float v = lpc[j * T_FRAMES + frame];
    out4[gi] = make_float4(v, v, v, v);
  }
}

extern "C" void kernel_launch(void* const* d_in, const int* in_sizes, int n_in,
                              void* d_out, int out_size, void* d_ws, size_t ws_size,
                              hipStream_t stream) {
  const float* mel = (const float*)d_in[0];
  const float* B   = (const float*)d_in[1];
  const float* lag = (const float*)d_in[2];
  float* ws = (float*)d_ws;
  unsigned short* bimg = (unsigned short*)ws;   // 256 KB frag-ready B
  float* lpcw = ws + 65536;                     // 256 KB lpc[4][16384]
  build_bimg<<<64, 256, 0, stream>>>(B, bimg);
  mel2lpc_mfma<<<T_FRAMES / FPB, BT, 0, stream>>>(mel, B, lag, bimg, lpcw);
  expand<<<2048, 256, 0, stream>>>(lpcw, (float4*)d_out);
}

// Round 8
// 94.846 us; speedup vs baseline: 1.6449x; 1.0283x over previous
//
#include <hip/hip_runtime.h>

#define T_FRAMES 16384
#define N_MELS 128
#define N_FREQ 513
#define FPB 32             // frames per block
#define BT 512             // 8 waves
#define LOG2_10 3.3219280948873623f

typedef short bf16x8 __attribute__((ext_vector_type(8)));
typedef unsigned short u16x8 __attribute__((ext_vector_type(8)));
typedef float f32x4 __attribute__((ext_vector_type(4)));

__device__ __forceinline__ unsigned short f2bf(float x) {
  unsigned u = __float_as_uint(x);
  return (unsigned short)((u + 0x7FFFu + ((u >> 16) & 1u)) >> 16);
}
__device__ __forceinline__ float bf2f(unsigned short h) {
  return __uint_as_float(((unsigned)h) << 16);
}

// ---- Kernel 0: build frag-ready bf16 hi/lo image of B -------------------
// gid bits [w:3][ft:2][ks:2][hl:1][l:6]; lane l of frag (w,ft,ks,hl) holds
// B[f][k0..k0+8) bf16, f = w*64+ft*16+(l&15), k0 = ks*32+(l>>4)*8.
__global__ __launch_bounds__(256) void build_bimg(
    const float* __restrict__ B, unsigned short* __restrict__ img) {
  int gid = blockIdx.x * 256 + threadIdx.x;   // 0..16383
  int l  = gid & 63;
  int hl = (gid >> 6) & 1;
  int ks = (gid >> 7) & 3;
  int ft = (gid >> 9) & 3;
  int w  = gid >> 11;
  int f  = w * 64 + ft * 16 + (l & 15);
  int k0 = ks * 32 + (l >> 4) * 8;
  const float* src = B + f * N_MELS + k0;
  u16x8 o;
#pragma unroll
  for (int j = 0; j < 8; ++j) {
    float x = src[j];
    unsigned short hi = f2bf(x);
    o[j] = hl ? f2bf(x - bf2f(hi)) : hi;
  }
  *((u16x8*)img + gid) = o;
}

// ---- Kernel A: fused MFMA GEMM + cos transform + Levinson + expand ------
// LDS overlay plan (bytes):
//   [0, 16896)      X32T float[32][132]   -- dead after frag build / f512
//     overlay:      red  float[8][5][32] at 0      (5120 B)
//                   lp   float[4][32]    at 5120   (512 B)
//   [16896, 33280)  Xf   short[16][512]
//   [33280, 43540)  W_s  float[5][513]
//   [43552, 43680)  pv512 float[32]
#define SM_X32T 0
#define SM_RED  0
#define SM_LP   5120
#define SM_XF   16896
#define SM_W    33280
#define SM_PV   43552
#define SM_SIZE 43712

__global__ __launch_bounds__(BT, 4) void mel2lpc_mfma(
    const float* __restrict__ mel,   // [128][16384]
    const float* __restrict__ B,     // [513][128] (row 512 only)
    const float* __restrict__ lag,   // [5]
    const unsigned short* __restrict__ bimg,
    float* __restrict__ out)         // [4][16384*256]
{
  __shared__ __align__(16) char smem[SM_SIZE];
  float (*X32T)[132] = (float(*)[132])(smem + SM_X32T);
  short (*Xf)[512]   = (short(*)[512])(smem + SM_XF);
  float (*W_s)[513]  = (float(*)[513])(smem + SM_W);
  float (*red)[5][32] = (float(*)[5][32])(smem + SM_RED);
  float (*lp)[32]    = (float(*)[32])(smem + SM_LP);
  float* pv512       = (float*)(smem + SM_PV);

  const int tid = threadIdx.x;
  const int lane = tid & 63;
  const int w = __builtin_amdgcn_readfirstlane(tid >> 6);
  const int t0 = blockIdx.x * FPB;

  // ---- Phase 0a: W[k][f] = lag[k]*cf*cos(2*pi*k*f/1024) (no int div) ----
#pragma unroll
  for (int k = 0; k < 5; ++k) {
    float lk = lag[k];
    for (int f = tid; f < N_FREQ; f += BT) {
      float cf = (f == 0 || f == N_FREQ - 1) ? (1.0f / 1024.0f) : (2.0f / 1024.0f);
      W_s[k][f] = lk * cf * cospif((float)(k * f) * (1.0f / 512.0f));
    }
  }
  // ---- Phase 0b: stage X^T = 10^mel ----
#pragma unroll
  for (int r = 0; r < 8; ++r) {
    int idx = r * BT + tid;    // 0..4095
    int t = idx & 31;
    int m = idx >> 5;
    X32T[t][m] = exp2f(mel[m * T_FRAMES + t0 + t] * LOG2_10);
  }
  __syncthreads();

  // ---- Phase 1a: f=512 row power (before X32T dies) ----
  if (tid < FPB) {
    const int t = tid;
    float s = 0.f;
    const float4* __restrict__ B512 = (const float4*)(B + 512 * N_MELS);
#pragma unroll
    for (int mi = 0; mi < 32; ++mi) {
      float4 b = B512[mi];
      float4 xv = *(const float4*)&X32T[t][mi * 4];
      s = fmaf(b.x, xv.x, s); s = fmaf(b.y, xv.y, s);
      s = fmaf(b.z, xv.z, s); s = fmaf(b.w, xv.w, s);
    }
    float lin = fmaxf(s, 1e-12f);
    pv512[t] = lin * lin;
  }
  // ---- Phase 1b: build X frags (wave w builds frag-pair w) ----
  {
    int tt = w >> 2, ks = w & 3;           // tt in {0,1}
    int t = tt * 16 + (lane & 15);
    int k0 = ks * 32 + (lane >> 4) * 8;
    float4 a0 = *(const float4*)&X32T[t][k0];
    float4 a1 = *(const float4*)&X32T[t][k0 + 4];
    float xs[8] = {a0.x, a0.y, a0.z, a0.w, a1.x, a1.y, a1.z, a1.w};
    u16x8 vh, vl;
#pragma unroll
    for (int j = 0; j < 8; ++j) {
      unsigned short hi = f2bf(xs[j]);
      vh[j] = hi;
      vl[j] = f2bf(xs[j] - bf2f(hi));
    }
    *(u16x8*)&Xf[w * 2][lane * 8] = vh;
    *(u16x8*)&Xf[w * 2 + 1][lane * 8] = vl;
  }
  __syncthreads();   // X32T dead from here; red/lp overlay becomes legal

  // ---- Phase 2: MFMA GEMM, wave w owns f-rows [64w, 64w+64) x 32 t ----
  f32x4 acc[4][2];
#pragma unroll
  for (int ft = 0; ft < 4; ++ft)
#pragma unroll
    for (int tt = 0; tt < 2; ++tt) acc[ft][tt] = (f32x4){0.f, 0.f, 0.f, 0.f};

  const bf16x8* bfr = (const bf16x8*)bimg;
#pragma unroll
  for (int ks = 0; ks < 4; ++ks) {
    bf16x8 xh0 = *(const bf16x8*)&Xf[(0 * 4 + ks) * 2][lane * 8];
    bf16x8 xl0 = *(const bf16x8*)&Xf[(0 * 4 + ks) * 2 + 1][lane * 8];
    bf16x8 xh1 = *(const bf16x8*)&Xf[(1 * 4 + ks) * 2][lane * 8];
    bf16x8 xl1 = *(const bf16x8*)&Xf[(1 * 4 + ks) * 2 + 1][lane * 8];
#pragma unroll
    for (int ft = 0; ft < 4; ++ft) {
      int fr = ((w * 4 + ft) * 4 + ks) * 2;
      bf16x8 ah = bfr[fr * 64 + lane];
      bf16x8 al = bfr[(fr + 1) * 64 + lane];
      acc[ft][0] = __builtin_amdgcn_mfma_f32_16x16x32_bf16(ah, xh0, acc[ft][0], 0, 0, 0);
      acc[ft][0] = __builtin_amdgcn_mfma_f32_16x16x32_bf16(ah, xl0, acc[ft][0], 0, 0, 0);
      acc[ft][0] = __builtin_amdgcn_mfma_f32_16x16x32_bf16(al, xh0, acc[ft][0], 0, 0, 0);
      acc[ft][1] = __builtin_amdgcn_mfma_f32_16x16x32_bf16(ah, xh1, acc[ft][1], 0, 0, 0);
      acc[ft][1] = __builtin_amdgcn_mfma_f32_16x16x32_bf16(ah, xl1, acc[ft][1], 0, 0, 0);
      acc[ft][1] = __builtin_amdgcn_mfma_f32_16x16x32_bf16(al, xh1, acc[ft][1], 0, 0, 0);
    }
  }

  // ---- Phase 3: clamp/square + cos-weighted reduce over f ----
  // C map: col = lane&15 (t within tt tile), row = (lane>>4)*4 + j (f)
  float pk[5][2];
#pragma unroll
  for (int k = 0; k < 5; ++k)
#pragma unroll
    for (int tt = 0; tt < 2; ++tt) pk[k][tt] = 0.f;

#pragma unroll
  for (int ft = 0; ft < 4; ++ft) {
#pragma unroll
    for (int j = 0; j < 4; ++j) {
      int f = w * 64 + ft * 16 + ((lane >> 4) << 2) + j;
      float w0 = W_s[0][f], w1 = W_s[1][f], w2 = W_s[2][f];
      float w3 = W_s[3][f], w4 = W_s[4][f];
#pragma unroll
      for (int tt = 0; tt < 2; ++tt) {
        float lin = fmaxf(acc[ft][tt][j], 1e-12f);
        float p = lin * lin;
        pk[0][tt] = fmaf(w0, p, pk[0][tt]);
        pk[1][tt] = fmaf(w1, p, pk[1][tt]);
        pk[2][tt] = fmaf(w2, p, pk[2][tt]);
        pk[3][tt] = fmaf(w3, p, pk[3][tt]);
        pk[4][tt] = fmaf(w4, p, pk[4][tt]);
      }
    }
  }
#pragma unroll
  for (int k = 0; k < 5; ++k)
#pragma unroll
    for (int tt = 0; tt < 2; ++tt) {
      float v = pk[k][tt];
      v += __shfl_xor(v, 16);
      v += __shfl_xor(v, 32);
      if (lane < 16) red[w][k][tt * 16 + lane] = v;
    }
  __syncthreads();

  // ---- Phase 4: cross-wave sum + f=512 + Levinson-Durbin (1 lane/frame) --
  if (tid < FPB) {
    const int t = tid;
    float ac[5];
#pragma unroll
    for (int k = 0; k < 5; ++k) {
      float s = 0.f;
#pragma unroll
      for (int w2 = 0; w2 < 8; ++w2) s += red[w2][k][t];
      ac[k] = s + W_s[k][512] * pv512[t];
    }

    float E = ac[0];
    float k0 = ac[1] / E;
    E *= fmaxf(1.0f - k0 * k0, 1e-5f);
    float l0 = -k0;

    float a1 = ac[2] + l0 * ac[1];
    float k1 = a1 / E;
    E *= fmaxf(1.0f - k1 * k1, 1e-5f);
    float m0 = l0 - k1 * l0;
    float m1 = -k1;

    float a2 = ac[3] + m0 * ac[2] + m1 * ac[1];
    float k2 = a2 / E;
    E *= fmaxf(1.0f - k2 * k2, 1e-5f);
    float n0 = m0 - k2 * m1;
    float n1 = m1 - k2 * m0;
    float n2 = -k2;

    float a3 = ac[4] + n0 * ac[3] + n1 * ac[2] + n2 * ac[1];
    float k3 = a3 / E;
    float o0 = n0 - k3 * n2;
    float o1 = n1 - k3 * n1;
    float o2 = n2 - k3 * n0;
    float o3 = -k3;

    lp[0][t] = -o3;
    lp[1][t] = -o2;
    lp[2][t] = -o1;
    lp[3][t] = -o0;
  }
  __syncthreads();

  // ---- Phase 5: repeat-expand write, coalesced float4 ----
  // per block: 4 rows x 32 frames x 256 reps = 8192 float4
  float4* out4 = (float4*)out;
#pragma unroll
  for (int i = 0; i < 16; ++i) {
    int vid = i * BT + tid;       // 0..8191
    int j = vid >> 11;            // output row 0..3
    int rem = vid & 2047;         // float4 idx within block's row chunk
    int tl = rem >> 6;            // local frame 0..31 (wave-uniform)
    float v = lp[j][tl];
    out4[(size_t)j * (T_FRAMES * 256 / 4) + (size_t)t0 * 64 + rem] =
        make_float4(v, v, v, v);
  }
}

extern "C" void kernel_launch(void* const* d_in, const int* in_sizes, int n_in,
                              void* d_out, int out_size, void* d_ws, size_t ws_size,
                              hipStream_t stream) {
  const float* mel = (const float*)d_in[0];
  const float* B   = (const float*)d_in[1];
  const float* lag = (const float*)d_in[2];
  unsigned short* bimg = (unsigned short*)d_ws;   // 256 KB frag-ready B
  build_bimg<<<64, 256, 0, stream>>>(B, bimg);
  mel2lpc_mfma<<<T_FRAMES / FPB, BT, 0, stream>>>(mel, B, lag, bimg, (float*)d_out);
}